// Round 9
// baseline (7909.177 us; speedup 1.0000x reference)
//
#include <hip/hip_runtime.h>

// ---------------- problem constants ----------------
#define NN      16384      // total nodes
#define TSTEPS  32
#define SG      256        // graphs
#define NE      262144
#define NPANEL  24         // 22 panels for xl@Wih (21x384 + 128) + 2 for lh@Whh (384+128)
#define GSTRIDE 524288u    // 256*2048 floats per panel partial

// ---------------- workspace layout (float offsets) ----------------
#define OFF_ENC_MEM   0u
#define OFF_ENC_SPK   2097152u
#define OFF_C1_MEM    4194304u
#define OFF_C1_SPK    6291456u     // == xl [256][8192]
#define OFF_LH        8388608u
#define OFF_LC        8519680u
#define OFF_H1_MEM    8650752u
#define OFF_H1_SPK    8716288u
#define OFF_H2_MEM    8781824u
#define OFF_H2_SPK    8782848u
#define OFF_H2_SUM    8783872u
#define ZERO_FLOATS   8784896u     // everything below here zeroed each launch
#define OFF_BASES     8784896u
#define OFF_COMB      9833472u
#define OFF_GATES     10357760u    // 256 x 2048
#define OFF_PART      10882048u    // 24 x 256 x 2048 panel partials
#define OFF_DINV      23464960u
#define OFF_COLW      23481344u
#define FLOAT_END     23743488u
// int region (offsets from ibase)
#define IOFF_DEG      0
#define IOFF_FILL     16384
#define IOFF_ROWPTR   32768
#define IOFF_EID      49153
#define IOFF_COL      311297
#define INT_COUNT     573441

// ---------------- graph preprocessing ----------------
__global__ void k_deg(const int* __restrict__ ei, int* __restrict__ deg) {
  int e = blockIdx.x * 256 + threadIdx.x;
  if (e < NE) atomicAdd(&deg[ei[NE + e]], 1);
}

__global__ void k_dinv(const int* __restrict__ deg, float* __restrict__ dinv) {
  int n = blockIdx.x * 256 + threadIdx.x;
  if (n < NN) dinv[n] = __fdiv_rn(1.0f, __fsqrt_rn((float)(deg[n] + 1)));  // +1 self-loop
}

__global__ void k_scan(const int* __restrict__ deg, int* __restrict__ rowp) {
  __shared__ int sdata[1024];
  int tid = threadIdx.x;
  int base = tid * 16;
  int loc[16];
  int sum = 0;
  #pragma unroll
  for (int i = 0; i < 16; ++i) { loc[i] = sum; sum += deg[base + i]; }
  sdata[tid] = sum;
  __syncthreads();
  for (int off = 1; off < 1024; off <<= 1) {
    int v = 0;
    if (tid >= off) v = sdata[tid - off];
    __syncthreads();
    sdata[tid] += v;
    __syncthreads();
  }
  int excl = (tid == 0) ? 0 : sdata[tid - 1];
  #pragma unroll
  for (int i = 0; i < 16; ++i) rowp[base + i] = excl + loc[i];
  if (tid == 1023) rowp[NN] = sdata[1023];
}

__global__ void k_scatter(const int* __restrict__ ei, const int* __restrict__ rowp,
                          int* __restrict__ fill, int* __restrict__ eid) {
  int e = blockIdx.x * 256 + threadIdx.x;
  if (e >= NE) return;
  int d = ei[NE + e];
  int pos = rowp[d] + atomicAdd(&fill[d], 1);
  eid[pos] = e;
}

// sort each adjacency list by EDGE ID (unique keys) -> summation order == scatter-add order
__global__ void k_sortadj(const int* __restrict__ rowp, int* __restrict__ eid,
                          const int* __restrict__ ei, const float* __restrict__ dinv,
                          int* __restrict__ col, float* __restrict__ colw) {
  int d = blockIdx.x * 256 + threadIdx.x;
  if (d >= NN) return;
  int r0 = rowp[d], r1 = rowp[d + 1];
  for (int i = r0 + 1; i < r1; ++i) {
    int key = eid[i];
    int j = i - 1;
    while (j >= r0 && eid[j] > key) { eid[j + 1] = eid[j]; --j; }
    eid[j + 1] = key;
  }
  for (int i = r0; i < r1; ++i) {
    int s = ei[eid[i]];
    col[i] = s;
    colw[i] = dinv[s];
  }
}

// ---------------- per-timestep kernels ----------------
// FUSED: enc LIF (in-block, 64 nodes) -> bases/comb GEMMs. 512 threads:
// 8 wave-roles (w0-3 bases 16ch, w4-7 comb 8ch). Per-(lane,ch) FMA chain j asc.
__global__ __launch_bounds__(512) void k_bases_comb(
    const float* __restrict__ x, const float* __restrict__ encW, const float* __restrict__ encB,
    float* __restrict__ enc_mem, float* __restrict__ enc_spk,
    const float* __restrict__ basesW, const float* __restrict__ basesB,
    const float* __restrict__ combW, const float* __restrict__ combB,
    float* __restrict__ bases, float* __restrict__ comb, int t) {
  __shared__ float xs[64][8];      // staged inputs for this block's 64 nodes
  __shared__ float sp[64 * 129];   // [node][j], pad 129 -> (n+j)%32 banks
  __shared__ float ob[64 * 65];    // bases out [node][ch], pad 65
  __shared__ float oc[64 * 33];    // comb out [node][ch], pad 33
  const int tid = threadIdx.x;
  const int nb = blockIdx.x * 64;
  // stage x: 64 nodes x 8 channels (one element per thread)
  {
    int n = tid >> 3, c = tid & 7;
    xs[n][c] = x[(size_t)(nb + n) * 256 + (size_t)c * 32 + t];
  }
  __syncthreads();
  // enc LIF for this block's 64 nodes (identical op chain to old k_enc)
  #pragma unroll 4
  for (int k = 0; k < 16; ++k) {
    int idx = k * 512 + tid;
    int n = idx >> 7, j = idx & 127;   // n uniform per wave -> xs broadcast reads
    int gidx = nb * 128 + idx;
    float dot = 0.f;
    #pragma unroll
    for (int c = 0; c < 8; ++c) dot = __fmaf_rn(xs[n][c], encW[c * 128 + j], dot);
    float m = enc_mem[gidx], s = enc_spk[gidx];
    float nm = __fadd_rn(__fadd_rn(__fmul_rn(__fmul_rn(m, 0.2f), __fsub_rn(1.f, s)), dot), encB[j]);
    enc_mem[gidx] = nm;
    float spk = nm > 0.5f ? 1.f : 0.f;
    enc_spk[gidx] = spk;
    sp[n * 129 + j] = spk;
  }
  __syncthreads();
  const int lane = tid & 63;
  const int w = tid >> 6;              // 0..7
  const float* spn = sp + lane * 129;
  if (w < 4) {
    const int ch0 = w * 16;
    const float* Wp = basesW + ch0;
    float acc[16];
    #pragma unroll
    for (int c = 0; c < 16; ++c) acc[c] = 0.f;
    for (int j = 0; j < 128; ++j) {
      const float s = spn[j];
      const float* wr = Wp + j * 64;     // lane-invariant -> scalar loads
      #pragma unroll
      for (int c = 0; c < 16; ++c) acc[c] = __fmaf_rn(s, wr[c], acc[c]);
    }
    #pragma unroll
    for (int c = 0; c < 16; ++c) ob[lane * 65 + ch0 + c] = acc[c];
  } else {
    const int ch0 = (w - 4) * 8;
    const float* Wp = combW + ch0;
    float acc[8];
    #pragma unroll
    for (int c = 0; c < 8; ++c) acc[c] = 0.f;
    for (int j = 0; j < 128; ++j) {
      const float s = spn[j];
      const float* wr = Wp + j * 32;
      #pragma unroll
      for (int c = 0; c < 8; ++c) acc[c] = __fmaf_rn(s, wr[c], acc[c]);
    }
    #pragma unroll
    for (int c = 0; c < 8; ++c) oc[lane * 33 + ch0 + c] = acc[c];
  }
  __syncthreads();
  // coalesced stores with bias
  #pragma unroll
  for (int r = 0; r < 8; ++r) {
    int idx = r * 512 + tid;
    int n = idx >> 6, ch = idx & 63;
    bases[(size_t)(nb + n) * 64 + ch] = __fadd_rn(ob[n * 65 + ch], basesB[ch]);
  }
  #pragma unroll
  for (int r = 0; r < 4; ++r) {
    int idx = r * 512 + tid;
    int n = idx >> 5, ch = idx & 31;
    comb[(size_t)(nb + n) * 32 + ch] = __fadd_rn(oc[n * 33 + ch], combB[ch]);
  }
}

// fused: symnorm aggregation (edge-order scatter-add) -> einsum -> conv LIF -> c1 spike
// gather loop unrolled x4 (loads hoisted, fadd order unchanged -> bit-exact).
__global__ __launch_bounds__(256) void k_aggconv(
    const float* __restrict__ bases, const float* __restrict__ comb,
    const float* __restrict__ dinv, const int* __restrict__ rowp,
    const int* __restrict__ col, const float* __restrict__ colw,
    const float* __restrict__ convB,
    float* __restrict__ c1_mem, float* __restrict__ c1_spk) {
  __shared__ float aggl[4][64];
  __shared__ float combl[4][32];
  int w = threadIdx.x >> 6;
  int m = threadIdx.x & 63;
  int d = blockIdx.x * 4 + w;
  float dd = dinv[d];
  int r0 = rowp[d], r1 = rowp[d + 1];
  float acc = 0.f;
  int r = r0;
  for (; r + 4 <= r1; r += 4) {
    const int s0 = col[r], s1 = col[r + 1], s2 = col[r + 2], s3 = col[r + 3];
    const float w0 = colw[r], w1 = colw[r + 1], w2 = colw[r + 2], w3 = colw[r + 3];
    const float b0 = bases[(size_t)s0 * 64 + m];
    const float b1 = bases[(size_t)s1 * 64 + m];
    const float b2 = bases[(size_t)s2 * 64 + m];
    const float b3 = bases[(size_t)s3 * 64 + m];
    acc = __fadd_rn(acc, __fmul_rn(__fmul_rn(w0, dd), b0));
    acc = __fadd_rn(acc, __fmul_rn(__fmul_rn(w1, dd), b1));
    acc = __fadd_rn(acc, __fmul_rn(__fmul_rn(w2, dd), b2));
    acc = __fadd_rn(acc, __fmul_rn(__fmul_rn(w3, dd), b3));
  }
  for (; r < r1; ++r) {
    int s = col[r];
    float ew  = __fmul_rn(colw[r], dd);
    float upd = __fmul_rn(ew, bases[(size_t)s * 64 + m]);
    acc = __fadd_rn(acc, upd);
  }
  {
    float ew  = __fmul_rn(dd, dd);
    float upd = __fmul_rn(ew, bases[(size_t)d * 64 + m]);
    acc = __fadd_rn(acc, upd);
  }
  aggl[w][m] = acc;
  if (m < 32) combl[w][m] = comb[(size_t)d * 32 + m];
  __syncthreads();
  #pragma unroll
  for (int half = 0; half < 2; ++half) {
    int j = m + half * 64;
    int h = j >> 4, f = j & 15;
    float cv = 0.f;
    #pragma unroll
    for (int b = 0; b < 4; ++b)
      cv = __fadd_rn(cv, __fmul_rn(combl[w][h * 4 + b], aggl[w][b * 16 + f]));
    cv = __fadd_rn(cv, convB[j]);
    int idx = d * 128 + j;
    float cm = c1_mem[idx], cs = c1_spk[idx];
    float nm = __fadd_rn(__fmul_rn(__fmul_rn(cm, 0.2f), __fsub_rn(1.f, cs)), cv);
    c1_mem[idx] = nm;
    c1_spk[idx] = nm > 0.5f ? 1.f : 0.f;
  }
}

// one BLAS panel of the gates GEMM: part[z] = A[:, panel_z] @ B[panel_z, :]
// 256 threads, 128x128 tile, 8x8 frag (4 LDS reads / 64 FMA -- halves LDS
// pressure vs 8x4), double-buffered. B is staged via global_load_lds (direct
// HBM->LDS DMA, zero staging registers; rows unpadded 128f so the wave-linear
// dest matches: 1 wave = 2 rows, 2 issues/wave/tile). A reg-staged (2 float4)
// into padded/transposed Ast (2-way write aliasing is free). One barrier/tile;
// __syncthreads' vmcnt drain completes the gload_lds before the buffer is read.
// Per-output chain: single FMA chain ascending k (kt asc, kk asc) -- bit-exact.
__global__ __launch_bounds__(256) void k_gpanel(
    const float* __restrict__ xl, const float* __restrict__ lh,
    const float* __restrict__ Wih, const float* __restrict__ Whh,
    float* __restrict__ part) {
  __shared__ __align__(16) float Ast[2][16][132];   // [buf][k][m] transposed, padded
  __shared__ __align__(16) float Bs[2][16][128];    // [buf][k][n] UNPADDED (DMA dest)
  const int tid = threadIdx.x;
  const int tx = tid & 15, ty = tid >> 4;
  const int n0 = blockIdx.x * 128;
  const int m0 = blockIdx.y * 128;
  const int z  = blockIdx.z;

  const float* Asrc; const float* Bsrc; int lda, k0, klen;
  if (z < 22) { Asrc = xl; Bsrc = Wih; lda = 8192; k0 = z * 384; klen = (z == 21) ? 128 : 384; }
  else        { Asrc = lh; Bsrc = Whh; lda = 512;  k0 = (z == 22) ? 0 : 384; klen = (z == 22) ? 384 : 128; }

  float acc[8][8];
  #pragma unroll
  for (int i = 0; i < 8; ++i)
    #pragma unroll
    for (int j = 0; j < 8; ++j) acc[i][j] = 0.f;

  const int arow = tid >> 1;            // 0..127
  const int acol = (tid & 1) * 8;       // 0 or 8
  const int wid  = tid >> 6;            // wave 0..3
  const int lane = tid & 63;
  const int brow0 = wid * 4;            // wave's 4 B rows per tile
  const int blr  = lane >> 5;           // 0/1: which of the wave's row pair
  const int blc  = (lane & 31) * 4;     // float col within row

  const int nkt = klen >> 4;
  float4 va0, va1;                      // A staging only (8 VGPRs)

  // ---- stage tile 0 ----
  {
    const float* srcA = Asrc + (size_t)(m0 + arow) * lda + k0 + acol;
    va0 = ((const float4*)srcA)[0];
    va1 = ((const float4*)srcA)[1];
    const float* g0 = Bsrc + (size_t)(k0 + brow0 + blr) * 2048 + n0 + blc;
    __builtin_amdgcn_global_load_lds(
        (const __attribute__((address_space(1))) void*)g0,
        (__attribute__((address_space(3))) void*)&Bs[0][brow0][0], 16, 0, 0);
    __builtin_amdgcn_global_load_lds(
        (const __attribute__((address_space(1))) void*)(g0 + 2 * 2048),
        (__attribute__((address_space(3))) void*)&Bs[0][brow0 + 2][0], 16, 0, 0);
    Ast[0][acol + 0][arow] = va0.x; Ast[0][acol + 1][arow] = va0.y;
    Ast[0][acol + 2][arow] = va0.z; Ast[0][acol + 3][arow] = va0.w;
    Ast[0][acol + 4][arow] = va1.x; Ast[0][acol + 5][arow] = va1.y;
    Ast[0][acol + 6][arow] = va1.z; Ast[0][acol + 7][arow] = va1.w;
  }
  __syncthreads();   // drains vmcnt (gload_lds) + lgkm (ds_writes)

  for (int kt = 0; kt < nkt; ++kt) {
    const int cur = kt & 1;
    const bool more = (kt + 1 < nkt);
    if (more) {
      // issue next tile's staging NOW: B goes straight to the alternate LDS
      // buffer (its readers all crossed the previous barrier); A into regs.
      const int kb = k0 + ((kt + 1) << 4);
      const int nxt = cur ^ 1;
      const float* g0 = Bsrc + (size_t)(kb + brow0 + blr) * 2048 + n0 + blc;
      __builtin_amdgcn_global_load_lds(
          (const __attribute__((address_space(1))) void*)g0,
          (__attribute__((address_space(3))) void*)&Bs[nxt][brow0][0], 16, 0, 0);
      __builtin_amdgcn_global_load_lds(
          (const __attribute__((address_space(1))) void*)(g0 + 2 * 2048),
          (__attribute__((address_space(3))) void*)&Bs[nxt][brow0 + 2][0], 16, 0, 0);
      const float* srcA = Asrc + (size_t)(m0 + arow) * lda + kb + acol;
      va0 = ((const float4*)srcA)[0];
      va1 = ((const float4*)srcA)[1];
    }
    // compute current tile
    #pragma unroll
    for (int kk = 0; kk < 16; ++kk) {
      const float4 a0 = *(const float4*)&Ast[cur][kk][ty * 4];
      const float4 a1 = *(const float4*)&Ast[cur][kk][64 + ty * 4];
      const float4 b0 = *(const float4*)&Bs[cur][kk][tx * 4];
      const float4 b1 = *(const float4*)&Bs[cur][kk][64 + tx * 4];
      const float av[8] = {a0.x, a0.y, a0.z, a0.w, a1.x, a1.y, a1.z, a1.w};
      const float bv[8] = {b0.x, b0.y, b0.z, b0.w, b1.x, b1.y, b1.z, b1.w};
      #pragma unroll
      for (int i = 0; i < 8; ++i)
        #pragma unroll
        for (int j = 0; j < 8; ++j)
          acc[i][j] = __fmaf_rn(av[i], bv[j], acc[i][j]);
    }
    if (more) {
      const int nxt = cur ^ 1;
      // write staged A into the alternate buffer (readers crossed prev barrier)
      Ast[nxt][acol + 0][arow] = va0.x; Ast[nxt][acol + 1][arow] = va0.y;
      Ast[nxt][acol + 2][arow] = va0.z; Ast[nxt][acol + 3][arow] = va0.w;
      Ast[nxt][acol + 4][arow] = va1.x; Ast[nxt][acol + 5][arow] = va1.y;
      Ast[nxt][acol + 6][arow] = va1.z; Ast[nxt][acol + 7][arow] = va1.w;
      __syncthreads();   // A writes visible + B DMA drained; all done with cur
    }
  }

  float* dstz = part + (size_t)z * GSTRIDE + (size_t)m0 * 2048 + n0;
  #pragma unroll
  for (int i = 0; i < 8; ++i) {
    const int mr = ((i >> 2) << 6) + ty * 4 + (i & 3);
    float* row = dstz + (size_t)mr * 2048;
    *(float4*)(row + tx * 4)      = make_float4(acc[i][0], acc[i][1], acc[i][2], acc[i][3]);
    *(float4*)(row + 64 + tx * 4) = make_float4(acc[i][4], acc[i][5], acc[i][6], acc[i][7]);
  }
}

// combine panel partials strictly left-to-right (matches verified "tih += accP" chain)
__global__ __launch_bounds__(256) void k_combine(
    const float* __restrict__ part, const float* __restrict__ bih,
    const float* __restrict__ bhh, float* __restrict__ gates) {
  const int idx = blockIdx.x * 256 + threadIdx.x;    // m*2048 + u
  const float* p = part + idx;
  float tih = p[0];
  #pragma unroll
  for (int zz = 1; zz < 22; ++zz) tih = __fadd_rn(tih, p[(size_t)zz * GSTRIDE]);
  const float thh = __fadd_rn(p[22u * GSTRIDE], p[23u * GSTRIDE]);
  const int u = idx & 2047;
  gates[idx] = __fadd_rn(__fadd_rn(__fadd_rn(tih, bih[u]), thh), bhh[u]);
}

// fused: gate spikes -> LSTM cell -> fc1 LIF -> fc2 LIF -> h2 accum. 512 threads.
__global__ __launch_bounds__(512) void k_cell(
    const float* __restrict__ gates,
    float* __restrict__ lc, float* __restrict__ lh,
    const float* __restrict__ fc1W, const float* __restrict__ fc1b,
    const float* __restrict__ fc2W, const float* __restrict__ fc2b,
    float* __restrict__ h1_mem, float* __restrict__ h1_spk,
    float* __restrict__ h2_mem, float* __restrict__ h2_spk, float* __restrict__ h2_sum) {
  __shared__ float lhl[512];
  __shared__ float a1buf[256];
  __shared__ float sp1l[256];
  const int s = blockIdx.x;
  const int tid = threadIdx.x;
  {
    const int h = tid;
    const float giv = gates[(size_t)s * 2048 + h];
    const float gfv = gates[(size_t)s * 2048 + 512 + h];
    const float ggv = gates[(size_t)s * 2048 + 1024 + h];
    const float gov = gates[(size_t)s * 2048 + 1536 + h];
    const float iv = giv > 0.f ? 1.f : 0.f;
    const float fv = gfv > 0.f ? 1.f : 0.f;
    const float gv = ggv > 0.f ? 1.f : 0.f;
    const float ov = gov > 0.f ? 1.f : 0.f;
    const int li = s * 512 + h;
    const float lcv = __fadd_rn(__fmul_rn(fv, lc[li]), __fmul_rn(iv, gv));
    lc[li] = lcv;
    const float lhv = __fmul_rn(lcv, ov);
    lh[li] = lhv;
    lhl[h] = lhv;
  }
  __syncthreads();
  float a0 = 0.f;
  if (tid < 256) {
    const int p = tid;
    #pragma unroll 8
    for (int q = 0; q < 384; ++q) a0 = __fmaf_rn(lhl[q], fc1W[q * 256 + p], a0);
  } else {
    const int p = tid - 256;
    float a1 = 0.f;
    #pragma unroll 8
    for (int q = 384; q < 512; ++q) a1 = __fmaf_rn(lhl[q], fc1W[q * 256 + p], a1);
    a1buf[p] = a1;
  }
  __syncthreads();
  if (tid < 256) {
    const int p = tid;
    const float dot1 = __fadd_rn(a0, a1buf[p]);
    const int i1 = s * 256 + p;
    const float m1 = h1_mem[i1], s1o = h1_spk[i1];
    const float nm1 = __fadd_rn(__fadd_rn(__fmul_rn(__fmul_rn(m1, 0.2f), __fsub_rn(1.f, s1o)), dot1), fc1b[p]);
    h1_mem[i1] = nm1;
    const float sp1 = nm1 > 0.5f ? 1.f : 0.f;
    h1_spk[i1] = sp1;
    sp1l[p] = sp1;
  }
  __syncthreads();
  if (tid < 4) {
    const int p = tid;
    float acc = 0.f;
    for (int q = 0; q < 256; ++q) acc = __fmaf_rn(sp1l[q], fc2W[q * 4 + p], acc);
    const int i2 = s * 4 + p;
    const float m2 = h2_mem[i2], s2o = h2_spk[i2];
    const float nm2 = __fadd_rn(__fadd_rn(__fmul_rn(__fmul_rn(m2, 0.2f), __fsub_rn(1.f, s2o)), acc), fc2b[p]);
    h2_mem[i2] = nm2;
    const float sp2 = nm2 > 0.5f ? 1.f : 0.f;
    h2_spk[i2] = sp2;
    h2_sum[i2] = __fadd_rn(h2_sum[i2], sp2);
  }
}

__global__ void k_out(const float* __restrict__ h2_sum, float* __restrict__ out) {
  int i = blockIdx.x * 256 + threadIdx.x;
  if (i < SG * 4) out[i] = __fmul_rn(h2_sum[i], 0.03125f);
}

// ---------------- launch ----------------
extern "C" void kernel_launch(void* const* d_in, const int* in_sizes, int n_in,
                              void* d_out, int out_size, void* d_ws, size_t ws_size,
                              hipStream_t stream) {
  const float* x      = (const float*)d_in[0];
  const int*   ei     = (const int*)  d_in[1];
  const float* encW   = (const float*)d_in[2];
  const float* encB   = (const float*)d_in[3];
  const float* basesW = (const float*)d_in[4];
  const float* basesB = (const float*)d_in[5];
  const float* combW  = (const float*)d_in[6];
  const float* combB  = (const float*)d_in[7];
  const float* convB  = (const float*)d_in[8];
  const float* Wih    = (const float*)d_in[9];
  const float* Whh    = (const float*)d_in[10];
  const float* bih    = (const float*)d_in[11];
  const float* bhh    = (const float*)d_in[12];
  const float* fc1W   = (const float*)d_in[13];
  const float* fc1b   = (const float*)d_in[14];
  const float* fc2W   = (const float*)d_in[15];
  const float* fc2b   = (const float*)d_in[16];

  float* ws = (float*)d_ws;
  float* enc_mem = ws + OFF_ENC_MEM;
  float* enc_spk = ws + OFF_ENC_SPK;
  float* c1_mem  = ws + OFF_C1_MEM;
  float* c1_spk  = ws + OFF_C1_SPK;   // xl
  float* lhp     = ws + OFF_LH;
  float* lcp     = ws + OFF_LC;
  float* h1_mem  = ws + OFF_H1_MEM;
  float* h1_spk  = ws + OFF_H1_SPK;
  float* h2_mem  = ws + OFF_H2_MEM;
  float* h2_spk  = ws + OFF_H2_SPK;
  float* h2_sum  = ws + OFF_H2_SUM;
  float* bases   = ws + OFF_BASES;
  float* comb    = ws + OFF_COMB;
  float* gates   = ws + OFF_GATES;
  float* partp   = ws + OFF_PART;
  float* dinv    = ws + OFF_DINV;
  float* colw    = ws + OFF_COLW;
  int* ibase = (int*)((char*)d_ws + (size_t)FLOAT_END * 4);
  int* deg  = ibase + IOFF_DEG;
  int* fill = ibase + IOFF_FILL;
  int* rowp = ibase + IOFF_ROWPTR;
  int* eid  = ibase + IOFF_EID;
  int* col  = ibase + IOFF_COL;

  hipMemsetAsync(ws, 0, (size_t)ZERO_FLOATS * 4, stream);
  hipMemsetAsync(ibase, 0, 32768 * 4, stream);

  k_deg    <<<NE / 256, 256, 0, stream>>>(ei, deg);
  k_dinv   <<<NN / 256, 256, 0, stream>>>(deg, dinv);
  k_scan   <<<1, 1024, 0, stream>>>(deg, rowp);
  k_scatter<<<NE / 256, 256, 0, stream>>>(ei, rowp, fill, eid);
  k_sortadj<<<NN / 256, 256, 0, stream>>>(rowp, eid, ei, dinv, col, colw);

  for (int t = 0; t < TSTEPS; ++t) {
    k_bases_comb<<<NN / 64, 512, 0, stream>>>(x, encW, encB, enc_mem, enc_spk,
                                              basesW, basesB, combW, combB, bases, comb, t);
    k_aggconv   <<<NN / 4, 256, 0, stream>>>(bases, comb, dinv, rowp, col, colw, convB, c1_mem, c1_spk);
    k_gpanel    <<<dim3(16, 2, NPANEL), 256, 0, stream>>>(c1_spk, lhp, Wih, Whh, partp);
    k_combine   <<<2048, 256, 0, stream>>>(partp, bih, bhh, gates);
    k_cell      <<<SG, 512, 0, stream>>>(gates, lcp, lhp, fc1W, fc1b, fc2W, fc2b,
                                         h1_mem, h1_spk, h2_mem, h2_spk, h2_sum);
  }
  k_out<<<4, 256, 0, stream>>>(h2_sum, (float*)d_out);
}

// Round 10
// 7240.601 us; speedup vs baseline: 1.0923x; 1.0923x over previous
//
#include <hip/hip_runtime.h>

// ---------------- problem constants ----------------
#define NN      16384      // total nodes
#define TSTEPS  32
#define SG      256        // graphs
#define NE      262144
#define NPANEL  24         // 22 panels for xl@Wih (21x384 + 128) + 2 for lh@Whh (384+128)
#define GSTRIDE 524288u    // 256*2048 floats per panel partial

// ---------------- workspace layout (float offsets) ----------------
#define OFF_ENC_MEM   0u
#define OFF_ENC_SPK   2097152u
#define OFF_C1_MEM    4194304u
#define OFF_C1_SPK    6291456u     // == xl [256][8192]
#define OFF_LH        8388608u
#define OFF_LC        8519680u
#define OFF_H1_MEM    8650752u
#define OFF_H1_SPK    8716288u
#define OFF_H2_MEM    8781824u
#define OFF_H2_SPK    8782848u
#define OFF_H2_SUM    8783872u
#define ZERO_FLOATS   8784896u     // everything below here zeroed each launch
#define OFF_BASES     8784896u
#define OFF_COMB      9833472u
#define OFF_GATES     10357760u    // 256 x 2048
#define OFF_PART      10882048u    // 24 x 256 x 2048 panel partials
#define OFF_DINV      23464960u
#define OFF_COLW      23481344u
#define FLOAT_END     23743488u
// int region (offsets from ibase)
#define IOFF_DEG      0
#define IOFF_FILL     16384
#define IOFF_ROWPTR   32768
#define IOFF_EID      49153
#define IOFF_COL      311297
#define INT_COUNT     573441

// ---------------- graph preprocessing ----------------
__global__ void k_deg(const int* __restrict__ ei, int* __restrict__ deg) {
  int e = blockIdx.x * 256 + threadIdx.x;
  if (e < NE) atomicAdd(&deg[ei[NE + e]], 1);
}

__global__ void k_dinv(const int* __restrict__ deg, float* __restrict__ dinv) {
  int n = blockIdx.x * 256 + threadIdx.x;
  if (n < NN) dinv[n] = __fdiv_rn(1.0f, __fsqrt_rn((float)(deg[n] + 1)));  // +1 self-loop
}

__global__ void k_scan(const int* __restrict__ deg, int* __restrict__ rowp) {
  __shared__ int sdata[1024];
  int tid = threadIdx.x;
  int base = tid * 16;
  int loc[16];
  int sum = 0;
  #pragma unroll
  for (int i = 0; i < 16; ++i) { loc[i] = sum; sum += deg[base + i]; }
  sdata[tid] = sum;
  __syncthreads();
  for (int off = 1; off < 1024; off <<= 1) {
    int v = 0;
    if (tid >= off) v = sdata[tid - off];
    __syncthreads();
    sdata[tid] += v;
    __syncthreads();
  }
  int excl = (tid == 0) ? 0 : sdata[tid - 1];
  #pragma unroll
  for (int i = 0; i < 16; ++i) rowp[base + i] = excl + loc[i];
  if (tid == 1023) rowp[NN] = sdata[1023];
}

__global__ void k_scatter(const int* __restrict__ ei, const int* __restrict__ rowp,
                          int* __restrict__ fill, int* __restrict__ eid) {
  int e = blockIdx.x * 256 + threadIdx.x;
  if (e >= NE) return;
  int d = ei[NE + e];
  int pos = rowp[d] + atomicAdd(&fill[d], 1);
  eid[pos] = e;
}

// sort each adjacency list by EDGE ID (unique keys) -> summation order == scatter-add order
__global__ void k_sortadj(const int* __restrict__ rowp, int* __restrict__ eid,
                          const int* __restrict__ ei, const float* __restrict__ dinv,
                          int* __restrict__ col, float* __restrict__ colw) {
  int d = blockIdx.x * 256 + threadIdx.x;
  if (d >= NN) return;
  int r0 = rowp[d], r1 = rowp[d + 1];
  for (int i = r0 + 1; i < r1; ++i) {
    int key = eid[i];
    int j = i - 1;
    while (j >= r0 && eid[j] > key) { eid[j + 1] = eid[j]; --j; }
    eid[j + 1] = key;
  }
  for (int i = r0; i < r1; ++i) {
    int s = ei[eid[i]];
    col[i] = s;
    colw[i] = dinv[s];
  }
}

// ---------------- per-timestep kernels ----------------
// FUSED: enc LIF (in-block, 64 nodes) -> bases/comb GEMMs. 512 threads:
// 8 wave-roles (w0-3 bases 16ch, w4-7 comb 8ch). Per-(lane,ch) FMA chain j asc.
__global__ __launch_bounds__(512) void k_bases_comb(
    const float* __restrict__ x, const float* __restrict__ encW, const float* __restrict__ encB,
    float* __restrict__ enc_mem, float* __restrict__ enc_spk,
    const float* __restrict__ basesW, const float* __restrict__ basesB,
    const float* __restrict__ combW, const float* __restrict__ combB,
    float* __restrict__ bases, float* __restrict__ comb, int t) {
  __shared__ float xs[64][8];      // staged inputs for this block's 64 nodes
  __shared__ float sp[64 * 129];   // [node][j], pad 129 -> (n+j)%32 banks
  __shared__ float ob[64 * 65];    // bases out [node][ch], pad 65
  __shared__ float oc[64 * 33];    // comb out [node][ch], pad 33
  const int tid = threadIdx.x;
  const int nb = blockIdx.x * 64;
  // stage x: 64 nodes x 8 channels (one element per thread)
  {
    int n = tid >> 3, c = tid & 7;
    xs[n][c] = x[(size_t)(nb + n) * 256 + (size_t)c * 32 + t];
  }
  __syncthreads();
  // enc LIF for this block's 64 nodes (identical op chain to old k_enc)
  #pragma unroll 4
  for (int k = 0; k < 16; ++k) {
    int idx = k * 512 + tid;
    int n = idx >> 7, j = idx & 127;   // n uniform per wave -> xs broadcast reads
    int gidx = nb * 128 + idx;
    float dot = 0.f;
    #pragma unroll
    for (int c = 0; c < 8; ++c) dot = __fmaf_rn(xs[n][c], encW[c * 128 + j], dot);
    float m = enc_mem[gidx], s = enc_spk[gidx];
    float nm = __fadd_rn(__fadd_rn(__fmul_rn(__fmul_rn(m, 0.2f), __fsub_rn(1.f, s)), dot), encB[j]);
    enc_mem[gidx] = nm;
    float spk = nm > 0.5f ? 1.f : 0.f;
    enc_spk[gidx] = spk;
    sp[n * 129 + j] = spk;
  }
  __syncthreads();
  const int lane = tid & 63;
  const int w = tid >> 6;              // 0..7
  const float* spn = sp + lane * 129;
  if (w < 4) {
    const int ch0 = w * 16;
    const float* Wp = basesW + ch0;
    float acc[16];
    #pragma unroll
    for (int c = 0; c < 16; ++c) acc[c] = 0.f;
    for (int j = 0; j < 128; ++j) {
      const float s = spn[j];
      const float* wr = Wp + j * 64;     // lane-invariant -> scalar loads
      #pragma unroll
      for (int c = 0; c < 16; ++c) acc[c] = __fmaf_rn(s, wr[c], acc[c]);
    }
    #pragma unroll
    for (int c = 0; c < 16; ++c) ob[lane * 65 + ch0 + c] = acc[c];
  } else {
    const int ch0 = (w - 4) * 8;
    const float* Wp = combW + ch0;
    float acc[8];
    #pragma unroll
    for (int c = 0; c < 8; ++c) acc[c] = 0.f;
    for (int j = 0; j < 128; ++j) {
      const float s = spn[j];
      const float* wr = Wp + j * 32;
      #pragma unroll
      for (int c = 0; c < 8; ++c) acc[c] = __fmaf_rn(s, wr[c], acc[c]);
    }
    #pragma unroll
    for (int c = 0; c < 8; ++c) oc[lane * 33 + ch0 + c] = acc[c];
  }
  __syncthreads();
  // coalesced stores with bias
  #pragma unroll
  for (int r = 0; r < 8; ++r) {
    int idx = r * 512 + tid;
    int n = idx >> 6, ch = idx & 63;
    bases[(size_t)(nb + n) * 64 + ch] = __fadd_rn(ob[n * 65 + ch], basesB[ch]);
  }
  #pragma unroll
  for (int r = 0; r < 4; ++r) {
    int idx = r * 512 + tid;
    int n = idx >> 5, ch = idx & 31;
    comb[(size_t)(nb + n) * 32 + ch] = __fadd_rn(oc[n * 33 + ch], combB[ch]);
  }
}

// fused: symnorm aggregation (edge-order scatter-add) -> einsum -> conv LIF -> c1 spike
// gather loop unrolled x4 (loads hoisted, fadd order unchanged -> bit-exact).
__global__ __launch_bounds__(256) void k_aggconv(
    const float* __restrict__ bases, const float* __restrict__ comb,
    const float* __restrict__ dinv, const int* __restrict__ rowp,
    const int* __restrict__ col, const float* __restrict__ colw,
    const float* __restrict__ convB,
    float* __restrict__ c1_mem, float* __restrict__ c1_spk) {
  __shared__ float aggl[4][64];
  __shared__ float combl[4][32];
  int w = threadIdx.x >> 6;
  int m = threadIdx.x & 63;
  int d = blockIdx.x * 4 + w;
  float dd = dinv[d];
  int r0 = rowp[d], r1 = rowp[d + 1];
  float acc = 0.f;
  int r = r0;
  for (; r + 4 <= r1; r += 4) {
    const int s0 = col[r], s1 = col[r + 1], s2 = col[r + 2], s3 = col[r + 3];
    const float w0 = colw[r], w1 = colw[r + 1], w2 = colw[r + 2], w3 = colw[r + 3];
    const float b0 = bases[(size_t)s0 * 64 + m];
    const float b1 = bases[(size_t)s1 * 64 + m];
    const float b2 = bases[(size_t)s2 * 64 + m];
    const float b3 = bases[(size_t)s3 * 64 + m];
    acc = __fadd_rn(acc, __fmul_rn(__fmul_rn(w0, dd), b0));
    acc = __fadd_rn(acc, __fmul_rn(__fmul_rn(w1, dd), b1));
    acc = __fadd_rn(acc, __fmul_rn(__fmul_rn(w2, dd), b2));
    acc = __fadd_rn(acc, __fmul_rn(__fmul_rn(w3, dd), b3));
  }
  for (; r < r1; ++r) {
    int s = col[r];
    float ew  = __fmul_rn(colw[r], dd);
    float upd = __fmul_rn(ew, bases[(size_t)s * 64 + m]);
    acc = __fadd_rn(acc, upd);
  }
  {
    float ew  = __fmul_rn(dd, dd);
    float upd = __fmul_rn(ew, bases[(size_t)d * 64 + m]);
    acc = __fadd_rn(acc, upd);
  }
  aggl[w][m] = acc;
  if (m < 32) combl[w][m] = comb[(size_t)d * 32 + m];
  __syncthreads();
  #pragma unroll
  for (int half = 0; half < 2; ++half) {
    int j = m + half * 64;
    int h = j >> 4, f = j & 15;
    float cv = 0.f;
    #pragma unroll
    for (int b = 0; b < 4; ++b)
      cv = __fadd_rn(cv, __fmul_rn(combl[w][h * 4 + b], aggl[w][b * 16 + f]));
    cv = __fadd_rn(cv, convB[j]);
    int idx = d * 128 + j;
    float cm = c1_mem[idx], cs = c1_spk[idx];
    float nm = __fadd_rn(__fmul_rn(__fmul_rn(cm, 0.2f), __fsub_rn(1.f, cs)), cv);
    c1_mem[idx] = nm;
    c1_spk[idx] = nm > 0.5f ? 1.f : 0.f;
  }
}

// one BLAS panel of the gates GEMM: part[z] = A[:, panel_z] @ B[panel_z, :]
// 512 threads, 128x128 tile, 8x4 frag, double-buffered with ZERO staging
// registers: both A and B tiles staged via global_load_lds (HBM->LDS DMA).
// A stored UNTRANSPOSED [row][16] (linear dest: wave w covers rows 16w..16w+15,
// thread slot = tid>>2); B [k][128] (wave w covers rows 2w..2w+1, slot tid>>5).
// Prefetch for buffer nxt issues BEFORE compute of cur; the barrier's vmcnt
// drain then completes an already-landed DMA -> true 2-deep pipeline.
// A-frag reads: per 4-kk chunk, 8 per-row float4 reads (2 distinct addrs/wave
// = free 2-way). FMA chain: kt asc, kk asc -- bit-exact vs reference chain.
__global__ __launch_bounds__(512) void k_gpanel(
    const float* __restrict__ xl, const float* __restrict__ lh,
    const float* __restrict__ Wih, const float* __restrict__ Whh,
    float* __restrict__ part) {
  __shared__ __align__(16) float Ast[2][128][16];   // [buf][row][k] UNPADDED (DMA dest)
  __shared__ __align__(16) float Bs[2][16][128];    // [buf][k][n]   UNPADDED (DMA dest)
  const int tid = threadIdx.x;
  const int tx = tid & 31;              // output cols tx*4..tx*4+3
  const int ty = tid >> 5;              // output rows ty*8..ty*8+7
  const int wid = tid >> 6;             // wave 0..7
  const int n0 = blockIdx.x * 128;
  const int m0 = blockIdx.y * 128;
  const int z  = blockIdx.z;

  const float* Asrc; const float* Bsrc; int lda, k0, klen;
  if (z < 22) { Asrc = xl; Bsrc = Wih; lda = 8192; k0 = z * 384; klen = (z == 21) ? 128 : 384; }
  else        { Asrc = lh; Bsrc = Whh; lda = 512;  k0 = (z == 22) ? 0 : 384; klen = (z == 22) ? 384 : 128; }

  float acc[8][4];
  #pragma unroll
  for (int i = 0; i < 8; ++i)
    #pragma unroll
    for (int j = 0; j < 4; ++j) acc[i][j] = 0.f;

  // DMA slot mapping (per thread, one 16B issue each for A and B per tile)
  const int adrow = tid >> 2;           // 0..127 (A row)
  const int adcol = (tid & 3) * 4;      // k-offset within row
  const int bdrow = tid >> 5;           // 0..15 (B row)
  const int bdcol = (tid & 31) * 4;     // col within row

  const int nkt = klen >> 4;

  // ---- prefetch tile 0 into buf 0 ----
  {
    const float* ga = Asrc + (size_t)(m0 + adrow) * lda + k0 + adcol;
    __builtin_amdgcn_global_load_lds(
        (const __attribute__((address_space(1))) void*)ga,
        (__attribute__((address_space(3))) void*)&Ast[0][wid * 16][0], 16, 0, 0);
    const float* gb = Bsrc + (size_t)(k0 + bdrow) * 2048 + n0 + bdcol;
    __builtin_amdgcn_global_load_lds(
        (const __attribute__((address_space(1))) void*)gb,
        (__attribute__((address_space(3))) void*)&Bs[0][wid * 2][0], 16, 0, 0);
  }
  __syncthreads();   // drains vmcnt -> tile 0 resident

  for (int kt = 0; kt < nkt; ++kt) {
    const int cur = kt & 1;
    const bool more = (kt + 1 < nkt);
    if (more) {   // prefetch next tile into the alternate buffer (readers done)
      const int kb = k0 + ((kt + 1) << 4);
      const int nxt = cur ^ 1;
      const float* ga = Asrc + (size_t)(m0 + adrow) * lda + kb + adcol;
      __builtin_amdgcn_global_load_lds(
          (const __attribute__((address_space(1))) void*)ga,
          (__attribute__((address_space(3))) void*)&Ast[nxt][wid * 16][0], 16, 0, 0);
      const float* gb = Bsrc + (size_t)(kb + bdrow) * 2048 + n0 + bdcol;
      __builtin_amdgcn_global_load_lds(
          (const __attribute__((address_space(1))) void*)gb,
          (__attribute__((address_space(3))) void*)&Bs[nxt][wid * 2][0], 16, 0, 0);
    }
    // compute current tile: 4 chunks of 4 kk
    #pragma unroll
    for (int c = 0; c < 4; ++c) {
      float ar[8][4];
      #pragma unroll
      for (int i = 0; i < 8; ++i) {
        const float4 v = *(const float4*)&Ast[cur][ty * 8 + i][c * 4];
        ar[i][0] = v.x; ar[i][1] = v.y; ar[i][2] = v.z; ar[i][3] = v.w;
      }
      #pragma unroll
      for (int q = 0; q < 4; ++q) {
        const float4 b0 = *(const float4*)&Bs[cur][c * 4 + q][tx * 4];
        const float bv[4] = {b0.x, b0.y, b0.z, b0.w};
        #pragma unroll
        for (int i = 0; i < 8; ++i)
          #pragma unroll
          for (int j = 0; j < 4; ++j)
            acc[i][j] = __fmaf_rn(ar[i][q], bv[j], acc[i][j]);
      }
    }
    if (more) __syncthreads();   // all waves done with cur; nxt DMA drained
  }

  float* dstz = part + (size_t)z * GSTRIDE + (size_t)m0 * 2048 + n0;
  #pragma unroll
  for (int i = 0; i < 8; ++i) {
    const int mr = ty * 8 + i;
    *(float4*)(dstz + (size_t)mr * 2048 + tx * 4) =
        make_float4(acc[i][0], acc[i][1], acc[i][2], acc[i][3]);
  }
}

// combine panel partials strictly left-to-right (matches verified "tih += accP" chain)
__global__ __launch_bounds__(256) void k_combine(
    const float* __restrict__ part, const float* __restrict__ bih,
    const float* __restrict__ bhh, float* __restrict__ gates) {
  const int idx = blockIdx.x * 256 + threadIdx.x;    // m*2048 + u
  const float* p = part + idx;
  float tih = p[0];
  #pragma unroll
  for (int zz = 1; zz < 22; ++zz) tih = __fadd_rn(tih, p[(size_t)zz * GSTRIDE]);
  const float thh = __fadd_rn(p[22u * GSTRIDE], p[23u * GSTRIDE]);
  const int u = idx & 2047;
  gates[idx] = __fadd_rn(__fadd_rn(__fadd_rn(tih, bih[u]), thh), bhh[u]);
}

// fused: gate spikes -> LSTM cell -> fc1 LIF -> fc2 LIF -> h2 accum. 512 threads.
__global__ __launch_bounds__(512) void k_cell(
    const float* __restrict__ gates,
    float* __restrict__ lc, float* __restrict__ lh,
    const float* __restrict__ fc1W, const float* __restrict__ fc1b,
    const float* __restrict__ fc2W, const float* __restrict__ fc2b,
    float* __restrict__ h1_mem, float* __restrict__ h1_spk,
    float* __restrict__ h2_mem, float* __restrict__ h2_spk, float* __restrict__ h2_sum) {
  __shared__ float lhl[512];
  __shared__ float a1buf[256];
  __shared__ float sp1l[256];
  const int s = blockIdx.x;
  const int tid = threadIdx.x;
  {
    const int h = tid;
    const float giv = gates[(size_t)s * 2048 + h];
    const float gfv = gates[(size_t)s * 2048 + 512 + h];
    const float ggv = gates[(size_t)s * 2048 + 1024 + h];
    const float gov = gates[(size_t)s * 2048 + 1536 + h];
    const float iv = giv > 0.f ? 1.f : 0.f;
    const float fv = gfv > 0.f ? 1.f : 0.f;
    const float gv = ggv > 0.f ? 1.f : 0.f;
    const float ov = gov > 0.f ? 1.f : 0.f;
    const int li = s * 512 + h;
    const float lcv = __fadd_rn(__fmul_rn(fv, lc[li]), __fmul_rn(iv, gv));
    lc[li] = lcv;
    const float lhv = __fmul_rn(lcv, ov);
    lh[li] = lhv;
    lhl[h] = lhv;
  }
  __syncthreads();
  float a0 = 0.f;
  if (tid < 256) {
    const int p = tid;
    #pragma unroll 8
    for (int q = 0; q < 384; ++q) a0 = __fmaf_rn(lhl[q], fc1W[q * 256 + p], a0);
  } else {
    const int p = tid - 256;
    float a1 = 0.f;
    #pragma unroll 8
    for (int q = 384; q < 512; ++q) a1 = __fmaf_rn(lhl[q], fc1W[q * 256 + p], a1);
    a1buf[p] = a1;
  }
  __syncthreads();
  if (tid < 256) {
    const int p = tid;
    const float dot1 = __fadd_rn(a0, a1buf[p]);
    const int i1 = s * 256 + p;
    const float m1 = h1_mem[i1], s1o = h1_spk[i1];
    const float nm1 = __fadd_rn(__fadd_rn(__fmul_rn(__fmul_rn(m1, 0.2f), __fsub_rn(1.f, s1o)), dot1), fc1b[p]);
    h1_mem[i1] = nm1;
    const float sp1 = nm1 > 0.5f ? 1.f : 0.f;
    h1_spk[i1] = sp1;
    sp1l[p] = sp1;
  }
  __syncthreads();
  if (tid < 4) {
    const int p = tid;
    float acc = 0.f;
    for (int q = 0; q < 256; ++q) acc = __fmaf_rn(sp1l[q], fc2W[q * 4 + p], acc);
    const int i2 = s * 4 + p;
    const float m2 = h2_mem[i2], s2o = h2_spk[i2];
    const float nm2 = __fadd_rn(__fadd_rn(__fmul_rn(__fmul_rn(m2, 0.2f), __fsub_rn(1.f, s2o)), acc), fc2b[p]);
    h2_mem[i2] = nm2;
    const float sp2 = nm2 > 0.5f ? 1.f : 0.f;
    h2_spk[i2] = sp2;
    h2_sum[i2] = __fadd_rn(h2_sum[i2], sp2);
  }
}

__global__ void k_out(const float* __restrict__ h2_sum, float* __restrict__ out) {
  int i = blockIdx.x * 256 + threadIdx.x;
  if (i < SG * 4) out[i] = __fmul_rn(h2_sum[i], 0.03125f);
}

// ---------------- launch ----------------
extern "C" void kernel_launch(void* const* d_in, const int* in_sizes, int n_in,
                              void* d_out, int out_size, void* d_ws, size_t ws_size,
                              hipStream_t stream) {
  const float* x      = (const float*)d_in[0];
  const int*   ei     = (const int*)  d_in[1];
  const float* encW   = (const float*)d_in[2];
  const float* encB   = (const float*)d_in[3];
  const float* basesW = (const float*)d_in[4];
  const float* basesB = (const float*)d_in[5];
  const float* combW  = (const float*)d_in[6];
  const float* combB  = (const float*)d_in[7];
  const float* convB  = (const float*)d_in[8];
  const float* Wih    = (const float*)d_in[9];
  const float* Whh    = (const float*)d_in[10];
  const float* bih    = (const float*)d_in[11];
  const float* bhh    = (const float*)d_in[12];
  const float* fc1W   = (const float*)d_in[13];
  const float* fc1b   = (const float*)d_in[14];
  const float* fc2W   = (const float*)d_in[15];
  const float* fc2b   = (const float*)d_in[16];

  float* ws = (float*)d_ws;
  float* enc_mem = ws + OFF_ENC_MEM;
  float* enc_spk = ws + OFF_ENC_SPK;
  float* c1_mem  = ws + OFF_C1_MEM;
  float* c1_spk  = ws + OFF_C1_SPK;   // xl
  float* lhp     = ws + OFF_LH;
  float* lcp     = ws + OFF_LC;
  float* h1_mem  = ws + OFF_H1_MEM;
  float* h1_spk  = ws + OFF_H1_SPK;
  float* h2_mem  = ws + OFF_H2_MEM;
  float* h2_spk  = ws + OFF_H2_SPK;
  float* h2_sum  = ws + OFF_H2_SUM;
  float* bases   = ws + OFF_BASES;
  float* comb    = ws + OFF_COMB;
  float* gates   = ws + OFF_GATES;
  float* partp   = ws + OFF_PART;
  float* dinv    = ws + OFF_DINV;
  float* colw    = ws + OFF_COLW;
  int* ibase = (int*)((char*)d_ws + (size_t)FLOAT_END * 4);
  int* deg  = ibase + IOFF_DEG;
  int* fill = ibase + IOFF_FILL;
  int* rowp = ibase + IOFF_ROWPTR;
  int* eid  = ibase + IOFF_EID;
  int* col  = ibase + IOFF_COL;

  hipMemsetAsync(ws, 0, (size_t)ZERO_FLOATS * 4, stream);
  hipMemsetAsync(ibase, 0, 32768 * 4, stream);

  k_deg    <<<NE / 256, 256, 0, stream>>>(ei, deg);
  k_dinv   <<<NN / 256, 256, 0, stream>>>(deg, dinv);
  k_scan   <<<1, 1024, 0, stream>>>(deg, rowp);
  k_scatter<<<NE / 256, 256, 0, stream>>>(ei, rowp, fill, eid);
  k_sortadj<<<NN / 256, 256, 0, stream>>>(rowp, eid, ei, dinv, col, colw);

  for (int t = 0; t < TSTEPS; ++t) {
    k_bases_comb<<<NN / 64, 512, 0, stream>>>(x, encW, encB, enc_mem, enc_spk,
                                              basesW, basesB, combW, combB, bases, comb, t);
    k_aggconv   <<<NN / 4, 256, 0, stream>>>(bases, comb, dinv, rowp, col, colw, convB, c1_mem, c1_spk);
    k_gpanel    <<<dim3(16, 2, NPANEL), 512, 0, stream>>>(c1_spk, lhp, Wih, Whh, partp);
    k_combine   <<<2048, 256, 0, stream>>>(partp, bih, bhh, gates);
    k_cell      <<<SG, 512, 0, stream>>>(gates, lcp, lhp, fc1W, fc1b, fc2W, fc2b,
                                         h1_mem, h1_spk, h2_mem, h2_spk, h2_sum);
  }
  k_out<<<4, 256, 0, stream>>>(h2_sum, (float*)d_out);
}

// Round 11
// 6090.992 us; speedup vs baseline: 1.2985x; 1.1887x over previous
//
#include <hip/hip_runtime.h>

// ---------------- problem constants ----------------
#define NN      16384      // total nodes
#define TSTEPS  32
#define SG      256        // graphs
#define NE      262144

// ---------------- workspace layout (float offsets) ----------------
#define OFF_ENC_MEM   0u
#define OFF_ENC_SPK   2097152u
#define OFF_C1_MEM    4194304u
#define OFF_C1_SPK    6291456u     // == xl [256][8192]
#define OFF_LH        8388608u
#define OFF_LC        8519680u
#define OFF_H1_MEM    8650752u
#define OFF_H1_SPK    8716288u
#define OFF_H2_MEM    8781824u
#define OFF_H2_SPK    8782848u
#define OFF_H2_SUM    8783872u
#define ZERO_FLOATS   8784896u     // everything below here zeroed each launch
#define OFF_BASES     8784896u
#define OFF_COMB      9833472u
#define OFF_GATES     10357760u    // 256 x 2048
#define OFF_DINV      23464960u
#define OFF_COLW      23481344u
#define FLOAT_END     23743488u
// int region (offsets from ibase)
#define IOFF_DEG      0
#define IOFF_FILL     16384
#define IOFF_ROWPTR   32768
#define IOFF_EID      49153
#define IOFF_COL      311297
#define INT_COUNT     573441

// ---------------- graph preprocessing ----------------
__global__ void k_deg(const int* __restrict__ ei, int* __restrict__ deg) {
  int e = blockIdx.x * 256 + threadIdx.x;
  if (e < NE) atomicAdd(&deg[ei[NE + e]], 1);
}

__global__ void k_dinv(const int* __restrict__ deg, float* __restrict__ dinv) {
  int n = blockIdx.x * 256 + threadIdx.x;
  if (n < NN) dinv[n] = __fdiv_rn(1.0f, __fsqrt_rn((float)(deg[n] + 1)));  // +1 self-loop
}

__global__ void k_scan(const int* __restrict__ deg, int* __restrict__ rowp) {
  __shared__ int sdata[1024];
  int tid = threadIdx.x;
  int base = tid * 16;
  int loc[16];
  int sum = 0;
  #pragma unroll
  for (int i = 0; i < 16; ++i) { loc[i] = sum; sum += deg[base + i]; }
  sdata[tid] = sum;
  __syncthreads();
  for (int off = 1; off < 1024; off <<= 1) {
    int v = 0;
    if (tid >= off) v = sdata[tid - off];
    __syncthreads();
    sdata[tid] += v;
    __syncthreads();
  }
  int excl = (tid == 0) ? 0 : sdata[tid - 1];
  #pragma unroll
  for (int i = 0; i < 16; ++i) rowp[base + i] = excl + loc[i];
  if (tid == 1023) rowp[NN] = sdata[1023];
}

__global__ void k_scatter(const int* __restrict__ ei, const int* __restrict__ rowp,
                          int* __restrict__ fill, int* __restrict__ eid) {
  int e = blockIdx.x * 256 + threadIdx.x;
  if (e >= NE) return;
  int d = ei[NE + e];
  int pos = rowp[d] + atomicAdd(&fill[d], 1);
  eid[pos] = e;
}

// sort each adjacency list by EDGE ID (unique keys) -> summation order == scatter-add order
__global__ void k_sortadj(const int* __restrict__ rowp, int* __restrict__ eid,
                          const int* __restrict__ ei, const float* __restrict__ dinv,
                          int* __restrict__ col, float* __restrict__ colw) {
  int d = blockIdx.x * 256 + threadIdx.x;
  if (d >= NN) return;
  int r0 = rowp[d], r1 = rowp[d + 1];
  for (int i = r0 + 1; i < r1; ++i) {
    int key = eid[i];
    int j = i - 1;
    while (j >= r0 && eid[j] > key) { eid[j + 1] = eid[j]; --j; }
    eid[j + 1] = key;
  }
  for (int i = r0; i < r1; ++i) {
    int s = ei[eid[i]];
    col[i] = s;
    colw[i] = dinv[s];
  }
}

// ---------------- per-timestep kernels ----------------
// FUSED: enc LIF (in-block, 64 nodes) -> bases/comb GEMMs. 512 threads.
__global__ __launch_bounds__(512) void k_bases_comb(
    const float* __restrict__ x, const float* __restrict__ encW, const float* __restrict__ encB,
    float* __restrict__ enc_mem, float* __restrict__ enc_spk,
    const float* __restrict__ basesW, const float* __restrict__ basesB,
    const float* __restrict__ combW, const float* __restrict__ combB,
    float* __restrict__ bases, float* __restrict__ comb, int t) {
  __shared__ float xs[64][8];      // staged inputs for this block's 64 nodes
  __shared__ float sp[64 * 129];   // [node][j], pad 129 -> (n+j)%32 banks
  __shared__ float ob[64 * 65];    // bases out [node][ch], pad 65
  __shared__ float oc[64 * 33];    // comb out [node][ch], pad 33
  const int tid = threadIdx.x;
  const int nb = blockIdx.x * 64;
  {
    int n = tid >> 3, c = tid & 7;
    xs[n][c] = x[(size_t)(nb + n) * 256 + (size_t)c * 32 + t];
  }
  __syncthreads();
  #pragma unroll 4
  for (int k = 0; k < 16; ++k) {
    int idx = k * 512 + tid;
    int n = idx >> 7, j = idx & 127;
    int gidx = nb * 128 + idx;
    float dot = 0.f;
    #pragma unroll
    for (int c = 0; c < 8; ++c) dot = __fmaf_rn(xs[n][c], encW[c * 128 + j], dot);
    float m = enc_mem[gidx], s = enc_spk[gidx];
    float nm = __fadd_rn(__fadd_rn(__fmul_rn(__fmul_rn(m, 0.2f), __fsub_rn(1.f, s)), dot), encB[j]);
    enc_mem[gidx] = nm;
    float spk = nm > 0.5f ? 1.f : 0.f;
    enc_spk[gidx] = spk;
    sp[n * 129 + j] = spk;
  }
  __syncthreads();
  const int lane = tid & 63;
  const int w = tid >> 6;
  const float* spn = sp + lane * 129;
  if (w < 4) {
    const int ch0 = w * 16;
    const float* Wp = basesW + ch0;
    float acc[16];
    #pragma unroll
    for (int c = 0; c < 16; ++c) acc[c] = 0.f;
    for (int j = 0; j < 128; ++j) {
      const float s = spn[j];
      const float* wr = Wp + j * 64;
      #pragma unroll
      for (int c = 0; c < 16; ++c) acc[c] = __fmaf_rn(s, wr[c], acc[c]);
    }
    #pragma unroll
    for (int c = 0; c < 16; ++c) ob[lane * 65 + ch0 + c] = acc[c];
  } else {
    const int ch0 = (w - 4) * 8;
    const float* Wp = combW + ch0;
    float acc[8];
    #pragma unroll
    for (int c = 0; c < 8; ++c) acc[c] = 0.f;
    for (int j = 0; j < 128; ++j) {
      const float s = spn[j];
      const float* wr = Wp + j * 32;
      #pragma unroll
      for (int c = 0; c < 8; ++c) acc[c] = __fmaf_rn(s, wr[c], acc[c]);
    }
    #pragma unroll
    for (int c = 0; c < 8; ++c) oc[lane * 33 + ch0 + c] = acc[c];
  }
  __syncthreads();
  #pragma unroll
  for (int r = 0; r < 8; ++r) {
    int idx = r * 512 + tid;
    int n = idx >> 6, ch = idx & 63;
    bases[(size_t)(nb + n) * 64 + ch] = __fadd_rn(ob[n * 65 + ch], basesB[ch]);
  }
  #pragma unroll
  for (int r = 0; r < 4; ++r) {
    int idx = r * 512 + tid;
    int n = idx >> 5, ch = idx & 31;
    comb[(size_t)(nb + n) * 32 + ch] = __fadd_rn(oc[n * 33 + ch], combB[ch]);
  }
}

// fused: symnorm aggregation -> einsum -> conv LIF -> c1 spike (x4 unrolled gather)
__global__ __launch_bounds__(256) void k_aggconv(
    const float* __restrict__ bases, const float* __restrict__ comb,
    const float* __restrict__ dinv, const int* __restrict__ rowp,
    const int* __restrict__ col, const float* __restrict__ colw,
    const float* __restrict__ convB,
    float* __restrict__ c1_mem, float* __restrict__ c1_spk) {
  __shared__ float aggl[4][64];
  __shared__ float combl[4][32];
  int w = threadIdx.x >> 6;
  int m = threadIdx.x & 63;
  int d = blockIdx.x * 4 + w;
  float dd = dinv[d];
  int r0 = rowp[d], r1 = rowp[d + 1];
  float acc = 0.f;
  int r = r0;
  for (; r + 4 <= r1; r += 4) {
    const int s0 = col[r], s1 = col[r + 1], s2 = col[r + 2], s3 = col[r + 3];
    const float w0 = colw[r], w1 = colw[r + 1], w2 = colw[r + 2], w3 = colw[r + 3];
    const float b0 = bases[(size_t)s0 * 64 + m];
    const float b1 = bases[(size_t)s1 * 64 + m];
    const float b2 = bases[(size_t)s2 * 64 + m];
    const float b3 = bases[(size_t)s3 * 64 + m];
    acc = __fadd_rn(acc, __fmul_rn(__fmul_rn(w0, dd), b0));
    acc = __fadd_rn(acc, __fmul_rn(__fmul_rn(w1, dd), b1));
    acc = __fadd_rn(acc, __fmul_rn(__fmul_rn(w2, dd), b2));
    acc = __fadd_rn(acc, __fmul_rn(__fmul_rn(w3, dd), b3));
  }
  for (; r < r1; ++r) {
    int s = col[r];
    float ew  = __fmul_rn(colw[r], dd);
    float upd = __fmul_rn(ew, bases[(size_t)s * 64 + m]);
    acc = __fadd_rn(acc, upd);
  }
  {
    float ew  = __fmul_rn(dd, dd);
    float upd = __fmul_rn(ew, bases[(size_t)d * 64 + m]);
    acc = __fadd_rn(acc, upd);
  }
  aggl[w][m] = acc;
  if (m < 32) combl[w][m] = comb[(size_t)d * 32 + m];
  __syncthreads();
  #pragma unroll
  for (int half = 0; half < 2; ++half) {
    int j = m + half * 64;
    int h = j >> 4, f = j & 15;
    float cv = 0.f;
    #pragma unroll
    for (int b = 0; b < 4; ++b)
      cv = __fadd_rn(cv, __fmul_rn(combl[w][h * 4 + b], aggl[w][b * 16 + f]));
    cv = __fadd_rn(cv, convB[j]);
    int idx = d * 128 + j;
    float cm = c1_mem[idx], cs = c1_spk[idx];
    float nm = __fadd_rn(__fmul_rn(__fmul_rn(cm, 0.2f), __fsub_rn(1.f, cs)), cv);
    c1_mem[idx] = nm;
    c1_spk[idx] = nm > 0.5f ? 1.f : 0.f;
  }
}

// SPARSE row-wise gates: one block per graph s; lanes cover all 2048 outputs
// (4 cols/thread). xl is BINARY -> the k-loop skips zero-spike rows with a
// WAVE-UNIFORM test (same (s,k) for all lanes). Skipping fma(0,w,acc) and
// using fadd for fma(1,w,acc) are value-exact. Chain order preserved exactly:
// per-panel sub-chains (k asc), folded left-to-right over the 22 ih-panels
// (384x21 + 128), then ((tih + bih) + (p22 + p23)) + bhh -- identical to the
// verified k_gpanel+k_combine chain. Nonzero-k list built in LDS (2-pass),
// walked with a depth-8 software pipeline (named float4 slots).
__global__ __launch_bounds__(512) void k_gates(
    const float* __restrict__ xl, const float* __restrict__ lh,
    const float* __restrict__ Wih, const float* __restrict__ Whh,
    const float* __restrict__ bih, const float* __restrict__ bhh,
    float* __restrict__ gates) {
  __shared__ unsigned short nzk[8192];
  __shared__ float lhs[512];
  __shared__ int wsum[9];
  const int tid = threadIdx.x;
  const int s = blockIdx.x;
  const int lane = tid & 63, wv = tid >> 6;
  const float* __restrict__ srow = xl + (size_t)s * 8192;

  // pass 1: count nonzeros in my 16-k chunk
  const int kb = tid * 16;
  int cnt = 0;
  #pragma unroll
  for (int i = 0; i < 16; ++i) cnt += (srow[kb + i] != 0.f) ? 1 : 0;
  // wave-inclusive prefix sum of counts
  int pfx = cnt;
  #pragma unroll
  for (int off = 1; off < 64; off <<= 1) {
    int tval = __shfl_up(pfx, off);
    if (lane >= off) pfx += tval;
  }
  if (lane == 63) wsum[wv] = pfx;
  __syncthreads();
  if (tid == 0) {
    int a = 0;
    #pragma unroll
    for (int w = 0; w < 8; ++w) { int tv = wsum[w]; wsum[w] = a; a += tv; }
    wsum[8] = a;
  }
  __syncthreads();
  const int off0 = wsum[wv] + (pfx - cnt);
  // pass 2: write ascending k-indices (no register-indexed arrays)
  {
    int c2 = 0;
    #pragma unroll
    for (int i = 0; i < 16; ++i) {
      if (srow[kb + i] != 0.f) { nzk[off0 + c2] = (unsigned short)(kb + i); ++c2; }
    }
  }
  lhs[tid] = lh[s * 512 + tid];
  __syncthreads();
  const int nnz = wsum[8];

  const int cl = tid * 4;
  const float* __restrict__ Wc = Wih + cl;
  float4 tih = make_float4(0.f, 0.f, 0.f, 0.f);
  float4 pz  = make_float4(0.f, 0.f, 0.f, 0.f);
  int zcur = 0, pend = 384;

#define FOLD(KK)                                                              \
  while ((KK) >= pend) {                                                      \
    tih.x = __fadd_rn(tih.x, pz.x); tih.y = __fadd_rn(tih.y, pz.y);           \
    tih.z = __fadd_rn(tih.z, pz.z); tih.w = __fadd_rn(tih.w, pz.w);           \
    pz.x = 0.f; pz.y = 0.f; pz.z = 0.f; pz.w = 0.f;                           \
    ++zcur; pend = (zcur < 21) ? (pend + 384) : 8192;                         \
  }

  // depth-8 pipeline (named slots; compile-time indices only)
  int k0_=0,k1_=0,k2_=0,k3_=0,k4_=0,k5_=0,k6_=0,k7_=0;
  float4 w0_,w1_,w2_,w3_,w4_,w5_,w6_,w7_;
#define PRELOAD(J, KS, WS)                                                    \
  if ((J) < nnz) { KS = nzk[(J)]; WS = *(const float4*)(Wc + (size_t)KS * 2048); }
  PRELOAD(0, k0_, w0_) PRELOAD(1, k1_, w1_) PRELOAD(2, k2_, w2_) PRELOAD(3, k3_, w3_)
  PRELOAD(4, k4_, w4_) PRELOAD(5, k5_, w5_) PRELOAD(6, k6_, w6_) PRELOAD(7, k7_, w7_)

#define STEP(KS, WS, BI, SO) {                                                \
    const int kcur = KS; const float4 wv4 = WS;                               \
    const int nidx = (BI) + (SO) + 8;                                         \
    if (nidx < nnz) { KS = nzk[nidx]; WS = *(const float4*)(Wc + (size_t)KS * 2048); } \
    FOLD(kcur);                                                               \
    pz.x = __fadd_rn(pz.x, wv4.x); pz.y = __fadd_rn(pz.y, wv4.y);             \
    pz.z = __fadd_rn(pz.z, wv4.z); pz.w = __fadd_rn(pz.w, wv4.w);             \
  }

  const int nmain = nnz & ~7;
  for (int i = 0; i < nmain; i += 8) {
    STEP(k0_, w0_, i, 0) STEP(k1_, w1_, i, 1) STEP(k2_, w2_, i, 2) STEP(k3_, w3_, i, 3)
    STEP(k4_, w4_, i, 4) STEP(k5_, w5_, i, 5) STEP(k6_, w6_, i, 6) STEP(k7_, w7_, i, 7)
  }
  for (int i = nmain; i < nnz; ++i) {
    const int kcur = nzk[i];
    const float4 wv4 = *(const float4*)(Wc + (size_t)kcur * 2048);
    FOLD(kcur);
    pz.x = __fadd_rn(pz.x, wv4.x); pz.y = __fadd_rn(pz.y, wv4.y);
    pz.z = __fadd_rn(pz.z, wv4.z); pz.w = __fadd_rn(pz.w, wv4.w);
  }
  // fold remaining panels (first adds current pz, rest add +0) -> 22 folds total
  for (; zcur < 22; ++zcur) {
    tih.x = __fadd_rn(tih.x, pz.x); tih.y = __fadd_rn(tih.y, pz.y);
    tih.z = __fadd_rn(tih.z, pz.z); tih.w = __fadd_rn(tih.w, pz.w);
    pz.x = 0.f; pz.y = 0.f; pz.z = 0.f; pz.w = 0.f;
  }
#undef STEP
#undef PRELOAD
#undef FOLD

  // dense lh @ Whh: panel 22 (k 0..383), panel 23 (k 384..511); thh = p22 + p23
  float4 p22 = make_float4(0.f, 0.f, 0.f, 0.f);
  #pragma unroll 4
  for (int k = 0; k < 384; ++k) {
    const float sv = lhs[k];
    const float4 wv4 = *(const float4*)(Whh + (size_t)k * 2048 + cl);
    p22.x = __fmaf_rn(sv, wv4.x, p22.x); p22.y = __fmaf_rn(sv, wv4.y, p22.y);
    p22.z = __fmaf_rn(sv, wv4.z, p22.z); p22.w = __fmaf_rn(sv, wv4.w, p22.w);
  }
  float4 p23 = make_float4(0.f, 0.f, 0.f, 0.f);
  #pragma unroll 4
  for (int k = 384; k < 512; ++k) {
    const float sv = lhs[k];
    const float4 wv4 = *(const float4*)(Whh + (size_t)k * 2048 + cl);
    p23.x = __fmaf_rn(sv, wv4.x, p23.x); p23.y = __fmaf_rn(sv, wv4.y, p23.y);
    p23.z = __fmaf_rn(sv, wv4.z, p23.z); p23.w = __fmaf_rn(sv, wv4.w, p23.w);
  }
  const float4 bi = *(const float4*)(bih + cl);
  const float4 bh = *(const float4*)(bhh + cl);
  float4 g;
  g.x = __fadd_rn(__fadd_rn(__fadd_rn(tih.x, bi.x), __fadd_rn(p22.x, p23.x)), bh.x);
  g.y = __fadd_rn(__fadd_rn(__fadd_rn(tih.y, bi.y), __fadd_rn(p22.y, p23.y)), bh.y);
  g.z = __fadd_rn(__fadd_rn(__fadd_rn(tih.z, bi.z), __fadd_rn(p22.z, p23.z)), bh.z);
  g.w = __fadd_rn(__fadd_rn(__fadd_rn(tih.w, bi.w), __fadd_rn(p22.w, p23.w)), bh.w);
  *(float4*)(gates + (size_t)s * 2048 + cl) = g;
}

// fused: gate spikes -> LSTM cell -> fc1 LIF -> fc2 LIF -> h2 accum. 512 threads.
__global__ __launch_bounds__(512) void k_cell(
    const float* __restrict__ gates,
    float* __restrict__ lc, float* __restrict__ lh,
    const float* __restrict__ fc1W, const float* __restrict__ fc1b,
    const float* __restrict__ fc2W, const float* __restrict__ fc2b,
    float* __restrict__ h1_mem, float* __restrict__ h1_spk,
    float* __restrict__ h2_mem, float* __restrict__ h2_spk, float* __restrict__ h2_sum) {
  __shared__ float lhl[512];
  __shared__ float a1buf[256];
  __shared__ float sp1l[256];
  const int s = blockIdx.x;
  const int tid = threadIdx.x;
  {
    const int h = tid;
    const float giv = gates[(size_t)s * 2048 + h];
    const float gfv = gates[(size_t)s * 2048 + 512 + h];
    const float ggv = gates[(size_t)s * 2048 + 1024 + h];
    const float gov = gates[(size_t)s * 2048 + 1536 + h];
    const float iv = giv > 0.f ? 1.f : 0.f;
    const float fv = gfv > 0.f ? 1.f : 0.f;
    const float gv = ggv > 0.f ? 1.f : 0.f;
    const float ov = gov > 0.f ? 1.f : 0.f;
    const int li = s * 512 + h;
    const float lcv = __fadd_rn(__fmul_rn(fv, lc[li]), __fmul_rn(iv, gv));
    lc[li] = lcv;
    const float lhv = __fmul_rn(lcv, ov);
    lh[li] = lhv;
    lhl[h] = lhv;
  }
  __syncthreads();
  float a0 = 0.f;
  if (tid < 256) {
    const int p = tid;
    #pragma unroll 8
    for (int q = 0; q < 384; ++q) a0 = __fmaf_rn(lhl[q], fc1W[q * 256 + p], a0);
  } else {
    const int p = tid - 256;
    float a1 = 0.f;
    #pragma unroll 8
    for (int q = 384; q < 512; ++q) a1 = __fmaf_rn(lhl[q], fc1W[q * 256 + p], a1);
    a1buf[p] = a1;
  }
  __syncthreads();
  if (tid < 256) {
    const int p = tid;
    const float dot1 = __fadd_rn(a0, a1buf[p]);
    const int i1 = s * 256 + p;
    const float m1 = h1_mem[i1], s1o = h1_spk[i1];
    const float nm1 = __fadd_rn(__fadd_rn(__fmul_rn(__fmul_rn(m1, 0.2f), __fsub_rn(1.f, s1o)), dot1), fc1b[p]);
    h1_mem[i1] = nm1;
    const float sp1 = nm1 > 0.5f ? 1.f : 0.f;
    h1_spk[i1] = sp1;
    sp1l[p] = sp1;
  }
  __syncthreads();
  if (tid < 4) {
    const int p = tid;
    float acc = 0.f;
    for (int q = 0; q < 256; ++q) acc = __fmaf_rn(sp1l[q], fc2W[q * 4 + p], acc);
    const int i2 = s * 4 + p;
    const float m2 = h2_mem[i2], s2o = h2_spk[i2];
    const float nm2 = __fadd_rn(__fadd_rn(__fmul_rn(__fmul_rn(m2, 0.2f), __fsub_rn(1.f, s2o)), acc), fc2b[p]);
    h2_mem[i2] = nm2;
    const float sp2 = nm2 > 0.5f ? 1.f : 0.f;
    h2_spk[i2] = sp2;
    h2_sum[i2] = __fadd_rn(h2_sum[i2], sp2);
  }
}

__global__ void k_out(const float* __restrict__ h2_sum, float* __restrict__ out) {
  int i = blockIdx.x * 256 + threadIdx.x;
  if (i < SG * 4) out[i] = __fmul_rn(h2_sum[i], 0.03125f);
}

// ---------------- launch ----------------
extern "C" void kernel_launch(void* const* d_in, const int* in_sizes, int n_in,
                              void* d_out, int out_size, void* d_ws, size_t ws_size,
                              hipStream_t stream) {
  const float* x      = (const float*)d_in[0];
  const int*   ei     = (const int*)  d_in[1];
  const float* encW   = (const float*)d_in[2];
  const float* encB   = (const float*)d_in[3];
  const float* basesW = (const float*)d_in[4];
  const float* basesB = (const float*)d_in[5];
  const float* combW  = (const float*)d_in[6];
  const float* combB  = (const float*)d_in[7];
  const float* convB  = (const float*)d_in[8];
  const float* Wih    = (const float*)d_in[9];
  const float* Whh    = (const float*)d_in[10];
  const float* bih    = (const float*)d_in[11];
  const float* bhh    = (const float*)d_in[12];
  const float* fc1W   = (const float*)d_in[13];
  const float* fc1b   = (const float*)d_in[14];
  const float* fc2W   = (const float*)d_in[15];
  const float* fc2b   = (const float*)d_in[16];

  float* ws = (float*)d_ws;
  float* enc_mem = ws + OFF_ENC_MEM;
  float* enc_spk = ws + OFF_ENC_SPK;
  float* c1_mem  = ws + OFF_C1_MEM;
  float* c1_spk  = ws + OFF_C1_SPK;   // xl
  float* lhp     = ws + OFF_LH;
  float* lcp     = ws + OFF_LC;
  float* h1_mem  = ws + OFF_H1_MEM;
  float* h1_spk  = ws + OFF_H1_SPK;
  float* h2_mem  = ws + OFF_H2_MEM;
  float* h2_spk  = ws + OFF_H2_SPK;
  float* h2_sum  = ws + OFF_H2_SUM;
  float* bases   = ws + OFF_BASES;
  float* comb    = ws + OFF_COMB;
  float* gates   = ws + OFF_GATES;
  float* dinv    = ws + OFF_DINV;
  float* colw    = ws + OFF_COLW;
  int* ibase = (int*)((char*)d_ws + (size_t)FLOAT_END * 4);
  int* deg  = ibase + IOFF_DEG;
  int* fill = ibase + IOFF_FILL;
  int* rowp = ibase + IOFF_ROWPTR;
  int* eid  = ibase + IOFF_EID;
  int* col  = ibase + IOFF_COL;

  hipMemsetAsync(ws, 0, (size_t)ZERO_FLOATS * 4, stream);
  hipMemsetAsync(ibase, 0, 32768 * 4, stream);

  k_deg    <<<NE / 256, 256, 0, stream>>>(ei, deg);
  k_dinv   <<<NN / 256, 256, 0, stream>>>(deg, dinv);
  k_scan   <<<1, 1024, 0, stream>>>(deg, rowp);
  k_scatter<<<NE / 256, 256, 0, stream>>>(ei, rowp, fill, eid);
  k_sortadj<<<NN / 256, 256, 0, stream>>>(rowp, eid, ei, dinv, col, colw);

  for (int t = 0; t < TSTEPS; ++t) {
    k_bases_comb<<<NN / 64, 512, 0, stream>>>(x, encW, encB, enc_mem, enc_spk,
                                              basesW, basesB, combW, combB, bases, comb, t);
    k_aggconv   <<<NN / 4, 256, 0, stream>>>(bases, comb, dinv, rowp, col, colw, convB, c1_mem, c1_spk);
    k_gates     <<<SG, 512, 0, stream>>>(c1_spk, lhp, Wih, Whh, bih, bhh, gates);
    k_cell      <<<SG, 512, 0, stream>>>(gates, lcp, lhp, fc1W, fc1b, fc2W, fc2b,
                                         h1_mem, h1_spk, h2_mem, h2_spk, h2_sum);
  }
  k_out<<<4, 256, 0, stream>>>(h2_sum, (float*)d_out);
}